// Round 6
// baseline (486.619 us; speedup 1.0000x reference)
//
#include <hip/hip_runtime.h>
#include <stdint.h>

typedef float v4f  __attribute__((ext_vector_type(4)));
typedef float v16f __attribute__((ext_vector_type(16)));
typedef int   v4i  __attribute__((ext_vector_type(4)));
typedef int   v8i  __attribute__((ext_vector_type(8)));

__device__ __forceinline__ void gload_lds16(const void* g, void* l) {
  __builtin_amdgcn_global_load_lds(
      (const __attribute__((address_space(1))) void*)g,
      (__attribute__((address_space(3))) void*)l, 16, 0, 0);
}
__device__ __forceinline__ void gload_lds4(const void* g, void* l) {
  __builtin_amdgcn_global_load_lds(
      (const __attribute__((address_space(1))) void*)g,
      (__attribute__((address_space(3))) void*)l, 4, 0, 0);
}

// ---------------------------------------------------------------------------
// Fused FWHT + MXFP4 quantize (proven; unchanged). k-major packed layout:
// group (kb,row) -> 16B at (kb*R+row)*16. Scales: dword (kt*2+hi)*R+row,
// byte ks (kt=kb>>3, hi=kb&1, ks=(kb>>1)&3).
// ---------------------------------------------------------------------------
__global__ __launch_bounds__(256) void quant_fp4_kernel(
    const float* __restrict__ in, uint32_t* __restrict__ packed,
    uint8_t* __restrict__ scales, int R, int rshift) {
  int g = blockIdx.x * 256 + threadIdx.x;
  int kb = g >> rshift, row = g & (R - 1);

  float v[32];
  const v4f* p = (const v4f*)(in + (size_t)row * 4096 + kb * 32);
#pragma unroll
  for (int c = 0; c < 8; ++c) {
    v4f t = p[c];
    v[c * 4 + 0] = t[0]; v[c * 4 + 1] = t[1];
    v[c * 4 + 2] = t[2]; v[c * 4 + 3] = t[3];
  }
#pragma unroll
  for (int s = 0; s < 5; ++s) {
    const int h = 1 << s;
#pragma unroll
    for (int k = 0; k < 16; ++k) {
      const int i = ((k >> s) << (s + 1)) | (k & (h - 1));
      float a = v[i], b = v[i + h];
      v[i] = a + b; v[i + h] = a - b;
    }
  }
  const float RS = 0.17677669529663687f;  // 32^-0.5
  float amax = 0.0f;
#pragma unroll
  for (int i = 0; i < 32; ++i) {
    v[i] *= RS;
    amax = fmaxf(amax, fabsf(v[i]));
  }
  int E;
  float rscale;
  if (amax > 0.0f) {
    float am = fmaxf(amax, 1e-30f);
    E = (int)((__float_as_uint(am) >> 23) & 255u) - 127;
    rscale = __uint_as_float((uint32_t)(2 - E + 127) << 23);
  } else { E = 2; rscale = 1.0f; }

  uint32_t dw[4] = {0u, 0u, 0u, 0u};
#pragma unroll
  for (int i = 0; i < 32; ++i) {
    float x = v[i];
    float a = fminf(fabsf(x) * rscale, 6.0f);
    float rstep = a >= 4.0f ? 0.5f : (a >= 2.0f ? 1.0f : 2.0f);
    float step  = a >= 4.0f ? 2.0f : (a >= 2.0f ? 1.0f : 0.5f);
    float q = rintf(a * rstep) * step;          // RNE onto e2m1 grid
    uint32_t uq = __float_as_uint(q);
    int Eq = (int)(uq >> 23) - 127;
    uint32_t code = (q == 0.0f) ? 0u
                  : (Eq < 0 ? 1u
                            : (((uint32_t)(Eq + 1) << 1) | ((uq >> 22) & 1u)));
    code |= (__float_as_uint(x) >> 31) << 3;
    dw[i >> 3] |= code << (4 * (i & 7));
  }
  uint4 o; o.x = dw[0]; o.y = dw[1]; o.z = dw[2]; o.w = dw[3];
  *(uint4*)(packed + (size_t)g * 4) = o;

  int kt = kb >> 3, hik = kb & 1, ks = (kb >> 1) & 3;
  scales[(size_t)((kt * 2 + hik) * R + row) * 4 + ks] = (uint8_t)(E - 2 + 127);
}

// ---------------------------------------------------------------------------
// MXFP4 GEMM, B^T, 256x256 tile, BK=256, 8 waves (2Mx4N), 4-phase/K-tile.
// Round-6 deltas vs round-5: undef-padded MFMA operands (no zero movs);
// fragment ds_reads pipelined one phase ahead with counted lgkmcnt(6)
// (+ sched_barrier fences, rule #18). vmcnt ledger identical to round 5.
// ---------------------------------------------------------------------------
#define MFMA4(a, b, c, sa, sb) \
  __builtin_amdgcn_mfma_scale_f32_32x32x64_f8f6f4((a), (b), (c), 4, 4, 0, (sa), 0, (sb))
#define PAD8(x) __builtin_shufflevector((x), (x), 0, 1, 2, 3, -1, -1, -1, -1)
#define BARRIER { asm volatile("" ::: "memory"); __builtin_amdgcn_s_barrier(); asm volatile("" ::: "memory"); }
#define SB0 __builtin_amdgcn_sched_barrier(0)
#define LGKM(n) { asm volatile("s_waitcnt lgkmcnt(" #n ")" ::: "memory"); SB0; }
#define VMW(n)  asm volatile("s_waitcnt vmcnt(" #n ")" ::: "memory")

__global__ __launch_bounds__(512, 2) void gemm_fp4_8ph(
    const uint8_t* __restrict__ Apk, const uint8_t* __restrict__ Bpk,
    const uint32_t* __restrict__ Asc, const uint32_t* __restrict__ Bsc,
    const float* __restrict__ bias, float* __restrict__ C) {
  const int N = 16384;
  __shared__ uint8_t lds[139264];

  const int tid = threadIdx.x, lane = tid & 63, wv = tid >> 6;
  const int wm = wv >> 2, wn = wv & 3;           // 2M x 4N waves
  const int hi = lane >> 5, r32 = lane & 31;

  // XCD-aware bijective swizzle (2048 blocks, 8m x 4n clusters per XCD)
  const int bid = blockIdx.x;
  const int xcd = bid & 7, idx = bid >> 3, st = idx >> 5;
  const int mT = ((st & 3) * 8 + (idx & 7)) * 256;
  const int nT = (xcd * 8 + (st >> 2) * 4 + ((idx >> 3) & 3)) * 256;

  // ---- operand staging map: per STG slot 16 instrs block-wide; wave issues 2
  const int sOp = wv >> 2;                 // 0:A 1:B
  const int sR2 = (wv >> 1) & 1;           // kc LSB
  const int s0  = 2 * (wv & 1);            // row-block base
  const uint8_t* opBase = sOp ? Bpk : Apk;
  const size_t RB = sOp ? (size_t)16384 * 16 : (size_t)8192 * 16;  // bytes/kb
  const int T0 = sOp ? nT : mT;
  const size_t gOff0 = (size_t)(T0 + (s0 + 0) * 64 + lane) * 16;
  const size_t gOff1 = (size_t)(T0 + (s0 + 1) * 64 + lane) * 16;
  const int dOff0 = sOp * 32768 + sR2 * 4096 + (s0 + 0) * 1024 + lane * 16;
  const int dOff1 = sOp * 32768 + sR2 * 4096 + (s0 + 1) * 1024 + lane * 16;

  auto STG_OPS = [&](int kt, int a, int bb) {
    const uint8_t* g0 = opBase + (size_t)(kt * 8 + a + sR2) * RB;
    uint8_t* l = &lds[bb * 65536 + a * 4096];
    gload_lds16(g0 + gOff0, l + dOff0);
    gload_lds16(g0 + gOff1, l + dOff1);
  };

  const uint32_t* scBase = sOp ? Bsc : Asc;
  const int Rrows = sOp ? 16384 : 8192;
  auto STG_SC = [&](int kt, int bb) {
    const uint32_t* g = scBase + (size_t)(kt * 2 + sR2) * Rrows + T0;
    uint8_t* l = &lds[131072 + bb * 4096 + sOp * 2048 + sR2 * 1024];
    gload_lds4(g + (s0 + 0) * 64 + lane, l + (s0 + 0) * 256 + lane * 4);
    gload_lds4(g + (s0 + 1) * 64 + lane, l + (s0 + 1) * 256 + lane * 4);
  };

  // ---- compute-side bases (per-buffer, so ds offsets stay in imm range)
  const int aRd0 = hi * 4096 + (wm * 128 + r32) * 16;
  const int aRd1 = aRd0 + 65536;
  const int bRd0 = 32768 + hi * 4096 + (wn * 64 + r32) * 16;
  const int bRd1 = bRd0 + 65536;
  const int aSc0 = 131072 + hi * 1024 + (wm * 128 + r32) * 4;
  const int aSc1 = aSc0 + 4096;
  const int bSc0 = 131072 + 2048 + hi * 1024 + (wn * 64 + r32) * 4;
  const int bSc1 = bSc0 + 4096;

  v16f acc[4][2] = {};
  v4i fA0[4], fB0[2], fA1[4], fB1[2];
  uint32_t saD[4], sbD[2];

#define LDF(FA, FB, ARD, BRD, j) { \
    _Pragma("unroll") for (int mf = 0; mf < 4; ++mf) \
      FA[mf] = *(const v4i*)&lds[(ARD) + (j) * 8192 + mf * 512]; \
    _Pragma("unroll") for (int nf = 0; nf < 2; ++nf) \
      FB[nf] = *(const v4i*)&lds[(BRD) + (j) * 8192 + nf * 512]; }

#define SCRD(ASC, BSC) { \
    _Pragma("unroll") for (int mf = 0; mf < 4; ++mf) \
      saD[mf] = *(const uint32_t*)&lds[(ASC) + mf * 128]; \
    _Pragma("unroll") for (int nf = 0; nf < 2; ++nf) \
      sbD[nf] = *(const uint32_t*)&lds[(BSC) + nf * 128]; }

#define MM8(FA, FB, j) { \
    __builtin_amdgcn_s_setprio(1); \
    _Pragma("unroll") for (int mf = 0; mf < 4; ++mf) \
    _Pragma("unroll") for (int nf = 0; nf < 2; ++nf) \
      acc[mf][nf] = MFMA4(PAD8(FA[mf]), PAD8(FB[nf]), acc[mf][nf], \
                          (int)((saD[mf] >> (8 * (j))) & 255u), \
                          (int)((sbD[nf] >> (8 * (j))) & 255u)); \
    __builtin_amdgcn_s_setprio(0); }

  // Full tile t in buffer bb (STG pattern identical to round 5):
  //  ph0: issue {SCRD, j0} | j1 ; STG(t+1,kc6,ob) ; BAR ; lgkm(6) ; MFMA j0 ; BAR
  //  ph1: issue j2 ; STG(t+2,kc0,bb)+SC(t+2,bb)   ; BAR ; lgkm(6) ; MFMA j1 ; BAR
  //  ph2: issue j3 ; STG(t+2,kc2,bb)              ; BAR ; lgkm(6) ; MFMA j2 ; BAR
  //  ph3:           STG(t+2,kc4,bb)               ; BAR ; lgkm(0) ; MFMA j3 ; VMW(8) ; BAR
#define TILE(bb, t, ARD, BRD, ASC, BSC, ob) { \
    SCRD(ASC, BSC); LDF(fA0, fB0, ARD, BRD, 0); SB0; LDF(fA1, fB1, ARD, BRD, 1); \
    STG_OPS((t) + 1, 6, ob); \
    BARRIER; LGKM(6); MM8(fA0, fB0, 0); BARRIER; \
    LDF(fA0, fB0, ARD, BRD, 2); \
    STG_OPS((t) + 2, 0, bb); STG_SC((t) + 2, bb); \
    BARRIER; LGKM(6); MM8(fA1, fB1, 1); BARRIER; \
    LDF(fA1, fB1, ARD, BRD, 3); \
    STG_OPS((t) + 2, 2, bb); \
    BARRIER; LGKM(6); MM8(fA0, fB0, 2); BARRIER; \
    STG_OPS((t) + 2, 4, bb); \
    BARRIER; LGKM(0); MM8(fA1, fB1, 3); \
    VMW(8); BARRIER; }

  // ---- prologue: tile0 full (10 ops), tile1 minus kc6,7 (8 ops)
  STG_OPS(0, 0, 0); STG_OPS(0, 2, 0); STG_OPS(0, 4, 0); STG_OPS(0, 6, 0);
  STG_SC(0, 0);
  STG_OPS(1, 0, 1); STG_OPS(1, 2, 1); STG_OPS(1, 4, 1);
  STG_SC(1, 1);
  VMW(8);   // tile0 resident; tile1's 8 ops in flight
  BARRIER;

  // ---- main: tiles 0..13 (7 iterations x {buf0, buf1})
#pragma unroll 1
  for (int i = 0; i < 7; ++i) {
    const int t0 = 2 * i;
    TILE(0, t0,     aRd0, bRd0, aSc0, bSc0, 1);
    TILE(1, t0 + 1, aRd1, bRd1, aSc1, bSc1, 0);
  }

  // ---- tail tile 14 (buf0): only STG is (15,kc6)->buf1; drain at boundary
  SCRD(aSc0, bSc0); LDF(fA0, fB0, aRd0, bRd0, 0); SB0; LDF(fA1, fB1, aRd0, bRd0, 1);
  STG_OPS(15, 6, 1);
  BARRIER; LGKM(6); MM8(fA0, fB0, 0); BARRIER;
  LDF(fA0, fB0, aRd0, bRd0, 2);
  BARRIER; LGKM(6); MM8(fA1, fB1, 1); BARRIER;
  LDF(fA1, fB1, aRd0, bRd0, 3);
  BARRIER; LGKM(6); MM8(fA0, fB0, 2); BARRIER;
  BARRIER; LGKM(0); MM8(fA1, fB1, 3);
  VMW(0); BARRIER;

  // ---- tail tile 15 (buf1): no staging, no vm waits
  SCRD(aSc1, bSc1); LDF(fA0, fB0, aRd1, bRd1, 0); SB0; LDF(fA1, fB1, aRd1, bRd1, 1);
  BARRIER; LGKM(6); MM8(fA0, fB0, 0); BARRIER;
  LDF(fA0, fB0, aRd1, bRd1, 2);
  BARRIER; LGKM(6); MM8(fA1, fB1, 1); BARRIER;
  LDF(fA1, fB1, aRd1, bRd1, 3);
  BARRIER; LGKM(6); MM8(fA0, fB0, 2); BARRIER;
  BARRIER; LGKM(0); MM8(fA1, fB1, 3);

  // ---- epilogue: 32x32 C/D layout col=lane&31, row=(q&3)+8*(q>>2)+4*hi
#pragma unroll
  for (int nf = 0; nf < 2; ++nf) {
    const int col = nT + wn * 64 + nf * 32 + r32;
    const float bv = bias[col];
#pragma unroll
    for (int mf = 0; mf < 4; ++mf) {
      const int rbase = mT + wm * 128 + mf * 32 + 4 * hi;
#pragma unroll
      for (int q = 0; q < 16; ++q) {
        const int rowl = (q & 3) + 8 * (q >> 2);
        C[(size_t)(rbase + rowl) * N + col] = acc[mf][nf][q] + bv;
      }
    }
  }
}

// ---------------------------------------------------------------------------
extern "C" void kernel_launch(void* const* d_in, const int* in_sizes, int n_in,
                              void* d_out, int out_size, void* d_ws, size_t ws_size,
                              hipStream_t stream) {
  const float* x    = (const float*)d_in[0];   // 8192 x 4096
  const float* w    = (const float*)d_in[1];   // 16384 x 4096
  const float* bias = (const float*)d_in[2];   // 16384
  float* out = (float*)d_out;                  // 8192 x 16384 fp32

  uint8_t* x_pk = (uint8_t*)d_ws;                        // 16 MB
  uint8_t* w_pk = x_pk + (size_t)16 * 1024 * 1024;       // 32 MB
  uint8_t* x_sc = w_pk + (size_t)32 * 1024 * 1024;       // 1 MB
  uint8_t* w_sc = x_sc + (size_t)1  * 1024 * 1024;       // 2 MB

  quant_fp4_kernel<<<4096, 256, 0, stream>>>(x, (uint32_t*)x_pk, x_sc, 8192, 13);
  quant_fp4_kernel<<<8192, 256, 0, stream>>>(w, (uint32_t*)w_pk, w_sc, 16384, 14);

  gemm_fp4_8ph<<<2048, dim3(512), 0, stream>>>(
      x_pk, w_pk, (const uint32_t*)x_sc, (const uint32_t*)w_sc, bias, out);
}